// Round 10
// baseline (51.403 us; speedup 1.0000x reference)
//
#include <hip/hip_runtime.h>
#include <math.h>

// Problem constants (B,T,D,H,L from the reference)
#define BB 4
#define TT 2048
#define DD 512
#define HH 8
#define EPS 1e-5f
#define SCALE 0.125f            // dh^-0.5, dh=64
#define WW ((size_t)DD * DD)

// Algebra (verified R7/R8): phase updates are per-row scalings; LN is
// scale-invariant, so all 4 phases decouple. rel[h] is affine in raw v:
//   rel[h] = rstd*( v.(g*m) - mean*sum(g*m) ) + sum(be*m)
// Pipeline: sums (masked sum of normalized rows) -> mphase2 (S-reduce +
// mask stats + ks + m, pre-transformed) -> final (dots + gates + scale).
// R10: final stages the 16 mp vectors in LDS once per block (was: every wave
// re-loading 32 KB through L1/L2 -> 256 MB of operand re-fetch traffic).

__device__ __forceinline__ float wred(float s) {
#pragma unroll
  for (int o = 32; o > 0; o >>= 1) s += __shfl_xor(s, o);
  return s;
}

__device__ __forceinline__ void ldf(const float* p, int lane, float f[8]) {
  float4 a = *reinterpret_cast<const float4*>(p + lane * 4);
  float4 c = *reinterpret_cast<const float4*>(p + 256 + lane * 4);
  f[0]=a.x; f[1]=a.y; f[2]=a.z; f[3]=a.w;
  f[4]=c.x; f[5]=c.y; f[6]=c.z; f[7]=c.w;
}

// ---------------------------------------------------------------------------
// K1: masked sum of normalized rows, both sides.
// Grid: 512 blocks, 256 threads; 32 rows/block. partial[(s*4+b)*64+tile][d]
// ---------------------------------------------------------------------------
__global__ __launch_bounds__(256) void sums_kernel(
    const float* __restrict__ xv, const float* __restrict__ xa,
    const int* __restrict__ vkpm, const int* __restrict__ akpm,
    float* __restrict__ partial)
{
  const int blk  = blockIdx.x;
  const int s    = blk >> 8;
  const int b    = (blk >> 6) & 3;
  const int tile = blk & 63;
  const int wave = threadIdx.x >> 6, lane = threadIdx.x & 63;
  const float* x  = s ? xa : xv;
  const int* kpm  = s ? akpm : vkpm;
  const int row0  = b * TT + tile * 32 + wave * 8;

  __shared__ float lds[4][DD];

  float acc[8] = {0.f,0.f,0.f,0.f,0.f,0.f,0.f,0.f};
  for (int r = 0; r < 8; ++r) {
    const int row = row0 + r;
    float v[8]; ldf(x + (size_t)row * DD, lane, v);
    float s1 = 0.f, s2 = 0.f;
#pragma unroll
    for (int k = 0; k < 8; ++k) { s1 += v[k]; s2 += v[k]*v[k]; }
    s1 = wred(s1); s2 = wred(s2);
    const float mean = s1 * (1.f / (float)DD);
    const float var  = s2 * (1.f / (float)DD) - mean * mean;
    const float rstd = rsqrtf(var + EPS);
    if (kpm[row] == 0) {          // wave-uniform
#pragma unroll
      for (int k = 0; k < 8; ++k) acc[k] += (v[k] - mean) * rstd;
    }
  }
#pragma unroll
  for (int k = 0; k < 4; ++k) {
    lds[wave][lane*4+k]       = acc[k];
    lds[wave][256+lane*4+k]   = acc[4+k];
  }
  __syncthreads();
  const int tid = threadIdx.x;
  float s0 = lds[0][tid] + lds[1][tid] + lds[2][tid] + lds[3][tid];
  float s1 = lds[0][tid+256] + lds[1][tid+256] + lds[2][tid+256] + lds[3][tid+256];
  float* p = partial + ((size_t)(s*4 + b) * 64 + tile) * DD;
  p[tid]       = s0;
  p[tid + 256] = s1;
}

// ---------------------------------------------------------------------------
// K2: per (p,b,h): inline S-reduce (16x redundant, L2), inline mask stats,
// ks[j] = fac*Wk[h*64+j,:].nsum, m -> emitted pre-transformed:
//   mp = g*m; sm = sum(mp); c = sum(be*m).  layer-0 h==0 blocks write fs.
// Grid: 4*4*8 = 128 blocks, 256 threads.
// ---------------------------------------------------------------------------
__global__ __launch_bounds__(256) void mphase2_kernel(
    const float* __restrict__ partial,
    const int* __restrict__ vkpm, const int* __restrict__ akpm,
    const float* __restrict__ Wq_v, const float* __restrict__ Wk_av,
    const float* __restrict__ Wq_a, const float* __restrict__ Wk_va,
    const float* __restrict__ vid_g, const float* __restrict__ vid_b,
    const float* __restrict__ aud_g, const float* __restrict__ aud_b,
    float* __restrict__ mp,         // (4,4,8,512)
    float* __restrict__ cv,         // (4,4,8)
    float* __restrict__ smv,        // (4,4,8)
    float* __restrict__ fs)         // (8,4): {fac, flag, cnt}
{
  const int blk = blockIdx.x;
  const int p = blk >> 5, b = (blk >> 3) & 3, h = blk & 7;
  const int layer = p >> 1;
  const int isA = ((p & 1) == 0);   // A phases: vid queries, aud keys
  const int tid = threadIdx.x, wave = tid >> 6, lane = tid & 63;

  __shared__ float4 red[256];
  __shared__ float nsum_s[DD];
  __shared__ float ksl[64];
  __shared__ float csh[4];
  __shared__ float cs2[4], ss2[4];

  const int ksb = (isA ? 1 : 0) * 4 + b;        // key side slot

  // inline S reduce over 64 tiles (t-split in halves, float4 per thread)
  {
    const int half = tid >> 7;                  // t in [0,32) or [32,64)
    const int i    = tid & 127;
    const float* pp = partial + ((size_t)ksb * 64 + half * 32) * DD + i * 4;
    float4 acc = make_float4(0.f, 0.f, 0.f, 0.f);
#pragma unroll 8
    for (int t = 0; t < 32; ++t) {
      float4 u = *reinterpret_cast<const float4*>(pp + (size_t)t * DD);
      acc.x += u.x; acc.y += u.y; acc.z += u.z; acc.w += u.w;
    }
    red[tid] = acc;
  }

  // inline mask count
  const int* mk = isA ? akpm : vkpm;
  {
    int cnt = 0;
#pragma unroll
    for (int q = 0; q < 8; ++q) cnt += (mk[b * TT + q * 256 + tid] == 0) ? 1 : 0;
    float fc = wred((float)cnt);
    if (lane == 0) csh[wave] = fc;
  }
  __syncthreads();
  if (tid < 128) {
    float4 a0 = red[tid], a1 = red[tid + 128];
    *reinterpret_cast<float4*>(&nsum_s[tid * 4]) =
        make_float4(a0.x + a1.x, a0.y + a1.y, a0.z + a1.z, a0.w + a1.w);
  }
  __syncthreads();

  const float vc   = csh[0] + csh[1] + csh[2] + csh[3];
  const float fac  = SCALE / fmaxf(vc, 1.f);
  const float cntf = vc;
  if (layer == 0 && h == 0 && tid == 0) {   // p=0 -> ksb=4+b, p=1 -> ksb=b
    fs[ksb * 4 + 0] = fac;
    fs[ksb * 4 + 1] = (vc > 0.f) ? 1.f : 0.f;
    fs[ksb * 4 + 2] = vc;
  }

  const float* g  = (isA ? vid_g : aud_g) + (size_t)layer * DD;
  const float* be = (isA ? vid_b : aud_b) + (size_t)layer * DD;
  const float* Wk = (isA ? Wk_av : Wk_va) + (size_t)layer * WW;
  const float* Wq = (isA ? Wq_v  : Wq_a ) + (size_t)layer * WW;

  float gv[8], bv[8], sv[8], nl[8];
  ldf(g, lane, gv); ldf(be, lane, bv);
  {
    float4 a = *reinterpret_cast<const float4*>(&nsum_s[lane * 4]);
    float4 c = *reinterpret_cast<const float4*>(&nsum_s[256 + lane * 4]);
    sv[0]=a.x; sv[1]=a.y; sv[2]=a.z; sv[3]=a.w;
    sv[4]=c.x; sv[5]=c.y; sv[6]=c.z; sv[7]=c.w;
  }
#pragma unroll
  for (int k = 0; k < 8; ++k) nl[k] = sv[k]*gv[k] + cntf*bv[k];

#pragma unroll 4
  for (int jj = 0; jj < 16; ++jj) {
    const int j = wave * 16 + jj;
    float w[8]; ldf(Wk + (size_t)(h*64 + j) * DD, lane, w);
    float sdot = w[0]*nl[0]+w[1]*nl[1]+w[2]*nl[2]+w[3]*nl[3]
               + w[4]*nl[4]+w[5]*nl[5]+w[6]*nl[6]+w[7]*nl[7];
    sdot = wred(sdot);
    if (lane == 0) ksl[j] = sdot * fac;
  }
  __syncthreads();

  float a0 = 0.f, a1 = 0.f;
  const float* base = Wq + (size_t)(h*64) * DD;
#pragma unroll 16
  for (int j = 0; j < 64; ++j) {
    const float kk = ksl[j];
    a0 += base[(size_t)j*DD + tid]       * kk;
    a1 += base[(size_t)j*DD + tid + 256] * kk;
  }

  // transform: mp = g*m; scalars c = sum be*m, sm = sum mp
  const float gq0 = g[tid], gq1 = g[tid + 256];
  const float bq0 = be[tid], bq1 = be[tid + 256];
  const float mp0 = a0 * gq0, mp1 = a1 * gq1;
  float* mo = mp + (((size_t)p*4 + b)*8 + h) * DD;
  mo[tid]       = mp0;
  mo[tid + 256] = mp1;

  float cp = a0*bq0 + a1*bq1;
  float sp = mp0 + mp1;
  cp = wred(cp); sp = wred(sp);
  if (lane == 0) { cs2[wave] = cp; ss2[wave] = sp; }
  __syncthreads();
  if (tid == 0) {
    const int idx = ((p*4 + b)*8 + h);
    cv[idx]  = cs2[0]+cs2[1]+cs2[2]+cs2[3];
    smv[idx] = ss2[0]+ss2[1]+ss2[2]+ss2[3];
  }
}

// ---------------------------------------------------------------------------
// K3: final gates + output. 4 rows per wave, 16 per block; mp staged in LDS
// once per block (conflict-free b128 reads: 16 B/lane contiguous).
// 64 dot partials -> 64-value halving butterfly; MLP lane-parallel, lanes 0..7.
// Grid: 2*4*128 = 1024 blocks, 256 threads.
// ---------------------------------------------------------------------------
__global__ __launch_bounds__(256) void final_kernel(
    const float* __restrict__ xv_in, const float* __restrict__ xa_in,
    const float* __restrict__ mp, const float* __restrict__ cv,
    const float* __restrict__ smv, const float* __restrict__ fs,
    const float* __restrict__ vg_W1, const float* __restrict__ vg_b1,
    const float* __restrict__ vg_W2, const float* __restrict__ vg_b2,
    const float* __restrict__ ag_W1, const float* __restrict__ ag_b1,
    const float* __restrict__ ag_W2, const float* __restrict__ ag_b2,
    float* __restrict__ out_v, float* __restrict__ out_a)
{
  const int blk = blockIdx.x;
  const int s = blk >> 9, b = (blk >> 7) & 3, tile = blk & 127;
  const int tid = threadIdx.x, lane = tid & 63;
  const int wave = tid >> 6;
  const float* x = s ? xa_in : xv_in;
  float* out     = s ? out_a : out_v;
  const int row0 = b * TT + tile * 16 + wave * 4;

  __shared__ float mplds[16][DD];     // 32 KB: j = l*8 + h
  __shared__ float mlp[2][161];
  __shared__ float cs[16], ss[16];

  // ---- issue x row loads + stats first (overlaps LDS staging) ----
  float v[4][8];
  float myMean = 0.f, myRstd = 1.f;
#pragma unroll
  for (int r = 0; r < 4; ++r) {
    ldf(x + (size_t)(row0 + r) * DD, lane, v[r]);
    float s1 = 0.f, s2 = 0.f;
#pragma unroll
    for (int k = 0; k < 8; ++k) { s1 += v[r][k]; s2 += v[r][k]*v[r][k]; }
    s1 = wred(s1); s2 = wred(s2);
    const float mean = s1 * (1.f / (float)DD);
    const float rstd = rsqrtf(s2 * (1.f / (float)DD) - mean*mean + EPS);
    if ((lane & 3) == r) { myMean = mean; myRstd = rstd; }
  }

  // ---- stage mp (2048 float4s, 8 per thread, coalesced) ----
  {
    const float* mpb0 = mp + ((size_t)(s*4 + b) * 8) * DD;        // l=0 -> p=s
    const float* mpb1 = mp + ((size_t)((2+s)*4 + b) * 8) * DD;    // l=1 -> p=2+s
#pragma unroll
    for (int i = tid; i < 2048; i += 256) {
      const int j = i >> 7, pos = i & 127;
      const float* src = (j < 8) ? (mpb0 + (size_t)j * DD) : (mpb1 + (size_t)(j-8) * DD);
      *reinterpret_cast<float4*>(&mplds[j][pos * 4]) =
          *reinterpret_cast<const float4*>(src + pos * 4);
    }
  }
  // ---- stage cv/smv and MLP params ----
  if (tid < 16) {
    const int l = tid >> 3, h = tid & 7;
    const int p = l*2 + s;
    cs[tid] = cv [((size_t)p*4 + b) * 8 + h];
    ss[tid] = smv[((size_t)p*4 + b) * 8 + h];
  } else if (tid >= 32 && tid < 193) {
    const int t = tid - 32;                 // 0..160
    const float* W1p = s ? ag_W1 : vg_W1;   // (2,16,8)
    const float* b1p = s ? ag_b1 : vg_b1;   // (2,16)
    const float* W2p = s ? ag_W2 : vg_W2;   // (2,16)
    const float* b2p = s ? ag_b2 : vg_b2;   // (2)
    if (t < 128)       { mlp[0][t] = W1p[t];       mlp[1][t] = W1p[128 + t]; }
    else if (t < 144)  { mlp[0][t] = b1p[t - 128]; mlp[1][t] = b1p[t - 112]; }
    else if (t < 160)  { mlp[0][t] = W2p[t - 144]; mlp[1][t] = W2p[t - 128]; }
    else               { mlp[0][160] = b2p[0];     mlp[1][160] = b2p[1]; }
  }
  __syncthreads();

  const float flag = fs[(((s ? 0 : 1) * 4) + b) * 4 + 1];   // key-mask side

  // 64 dot partials from LDS: a[r*16 + j] = v[r] . mplds[j] (lane's 8 elems)
  float a[64];
#pragma unroll
  for (int j = 0; j < 16; ++j) {
    float4 w0 = *reinterpret_cast<const float4*>(&mplds[j][lane * 4]);
    float4 w1 = *reinterpret_cast<const float4*>(&mplds[j][256 + lane * 4]);
#pragma unroll
    for (int r = 0; r < 4; ++r) {
      a[r*16 + j] = v[r][0]*w0.x + v[r][1]*w0.y + v[r][2]*w0.z + v[r][3]*w0.w
                  + v[r][4]*w1.x + v[r][5]*w1.y + v[r][6]*w1.z + v[r][7]*w1.w;
    }
  }

  // halving butterfly: lane L ends with full dot for idx L (R8-verified)
#pragma unroll
  for (int k = 0; k < 6; ++k) {
    const int bit = (lane >> k) & 1;
#pragma unroll
    for (int m = 0; m < (64 >> (k + 1)); ++m) {
      const float keep = bit ? a[2*m+1] : a[2*m];
      const float send = bit ? a[2*m]   : a[2*m+1];
      a[m] = keep + __shfl_xor(send, 1 << k);
    }
  }

  // gather: job lane jl in 0..7 -> (r = jl&3, l = jl>>2); dots at lanes
  // r*16 + l*8 + h. Executed by ALL lanes (shfl needs full wave).
  const int gr = lane & 3, gl = (lane >> 2) & 1;
  float q[8];
#pragma unroll
  for (int h = 0; h < HH; ++h) q[h] = __shfl(a[0], gr*16 + gl*8 + h);

  float gpart = 1.f;
  if (lane < 8) {
    const int l = lane >> 2;
    float rel[8];
#pragma unroll
    for (int h = 0; h < HH; ++h)
      rel[h] = myRstd * (q[h] - myMean * ss[l*8 + h]) + cs[l*8 + h];
    float z = mlp[l][160];
#pragma unroll
    for (int e = 0; e < 16; ++e) {
      float h1 = mlp[l][128 + e];
#pragma unroll
      for (int h = 0; h < HH; ++h) h1 += rel[h] * mlp[l][e*8 + h];
      z += fmaxf(h1, 0.f) * mlp[l][144 + e];
    }
    gpart = 1.f + flag * (1.f / (1.f + expf(-z)));
  }

#pragma unroll
  for (int r = 0; r < 4; ++r) {
    const float sc = __shfl(gpart, r) * __shfl(gpart, 4 + r);
    float* orow = out + (size_t)(row0 + r) * DD;
    *reinterpret_cast<float4*>(orow + lane*4) =
        make_float4(v[r][0]*sc, v[r][1]*sc, v[r][2]*sc, v[r][3]*sc);
    *reinterpret_cast<float4*>(orow + 256 + lane*4) =
        make_float4(v[r][4]*sc, v[r][5]*sc, v[r][6]*sc, v[r][7]*sc);
  }
}

// ---------------------------------------------------------------------------
extern "C" void kernel_launch(void* const* d_in, const int* in_sizes, int n_in,
                              void* d_out, int out_size, void* d_ws, size_t ws_size,
                              hipStream_t stream) {
  const float* x_vid = (const float*)d_in[0];
  const float* x_aud = (const float*)d_in[1];
  const int* vid_kpm = (const int*)d_in[2];
  const int* aud_kpm = (const int*)d_in[3];
  const float* Wq_vid         = (const float*)d_in[4];
  const float* Wk_aud_for_vid = (const float*)d_in[5];
  const float* Wq_aud         = (const float*)d_in[6];
  const float* Wk_vid_for_aud = (const float*)d_in[7];
  const float* vg_W1 = (const float*)d_in[8];
  const float* vg_b1 = (const float*)d_in[9];
  const float* vg_W2 = (const float*)d_in[10];
  const float* vg_b2 = (const float*)d_in[11];
  const float* ag_W1 = (const float*)d_in[12];
  const float* ag_b1 = (const float*)d_in[13];
  const float* ag_W2 = (const float*)d_in[14];
  const float* ag_b2 = (const float*)d_in[15];
  const float* vid_ln_g = (const float*)d_in[16];
  const float* vid_ln_b = (const float*)d_in[17];
  const float* aud_ln_g = (const float*)d_in[18];
  const float* aud_ln_b = (const float*)d_in[19];

  const size_t BTD = (size_t)BB * TT * DD;
  float* out_v = (float*)d_out;
  float* out_a = out_v + BTD;

  float* partial = (float*)d_ws;                       // 2*4*64*512 = 1 MB
  float* fs      = partial + (size_t)8 * 64 * DD;      // 8*4
  float* mpw     = fs + 32;                            // 4*4*8*512 = 256 KB
  float* cvw     = mpw + (size_t)4 * 4 * 8 * DD;       // 128
  float* smw     = cvw + 128;                          // 128

  sums_kernel<<<512, 256, 0, stream>>>(x_vid, x_aud, vid_kpm, aud_kpm, partial);
  mphase2_kernel<<<128, 256, 0, stream>>>(
      partial, vid_kpm, aud_kpm,
      Wq_vid, Wk_aud_for_vid, Wq_aud, Wk_vid_for_aud,
      vid_ln_g, vid_ln_b, aud_ln_g, aud_ln_b, mpw, cvw, smw, fs);
  final_kernel<<<1024, 256, 0, stream>>>(
      x_vid, x_aud, mpw, cvw, smw, fs,
      vg_W1, vg_b1, vg_W2, vg_b2, ag_W1, ag_b1, ag_W2, ag_b2,
      out_v, out_a);
}

// Round 11
// 42.075 us; speedup vs baseline: 1.2217x; 1.2217x over previous
//
#include <hip/hip_runtime.h>
#include <math.h>

// Problem constants (B,T,D,H,L from the reference)
#define BB 4
#define TT 2048
#define DD 512
#define HH 8
#define EPS 1e-5f
#define SCALE 0.125f            // dh^-0.5, dh=64
#define WW ((size_t)DD * DD)

// Algebra (verified R7/R8): phase updates are per-row scalings; LN is
// scale-invariant, so all 4 phases decouple. rel[h] is affine in raw v:
//   rel[h] = rstd*( v.(g*m) - mean*sum(g*m) ) + sum(be*m)
// R11: all multi-value cross-lane reductions use the halving butterfly
// (R8-verified): K values reduced in log2(64) shuffle steps instead of K
// serial 12-deep wred chains. sums persists per-row (mean,rstd) so final
// never recomputes stats.

__device__ __forceinline__ float wred(float s) {
#pragma unroll
  for (int o = 32; o > 0; o >>= 1) s += __shfl_xor(s, o);
  return s;
}

__device__ __forceinline__ void ldf(const float* p, int lane, float f[8]) {
  float4 a = *reinterpret_cast<const float4*>(p + lane * 4);
  float4 c = *reinterpret_cast<const float4*>(p + 256 + lane * 4);
  f[0]=a.x; f[1]=a.y; f[2]=a.z; f[3]=a.w;
  f[4]=c.x; f[5]=c.y; f[6]=c.z; f[7]=c.w;
}

// halving butterfly over K=16 values: afterwards the RETURN value on lane L
// is the full 64-lane sum of value idx (L & 15). (R8/R9-verified pattern.)
__device__ __forceinline__ float bfly16(float a[16], int lane) {
#pragma unroll
  for (int k = 0; k < 4; ++k) {
    const int bit = (lane >> k) & 1;
#pragma unroll
    for (int m = 0; m < (16 >> (k + 1)); ++m) {
      const float keep = bit ? a[2*m+1] : a[2*m];
      const float send = bit ? a[2*m]   : a[2*m+1];
      a[m] = keep + __shfl_xor(send, 1 << k);
    }
  }
  float r = a[0];
  r += __shfl_xor(r, 16);
  r += __shfl_xor(r, 32);
  return r;
}

// ---------------------------------------------------------------------------
// K1: masked sum of normalized rows, both sides; persists per-row stats.
// Grid: 512 blocks, 256 threads; 32 rows/block. partial[(s*4+b)*64+tile][d]
// ---------------------------------------------------------------------------
__global__ __launch_bounds__(256) void sums_kernel(
    const float* __restrict__ xv, const float* __restrict__ xa,
    const int* __restrict__ vkpm, const int* __restrict__ akpm,
    float* __restrict__ partial,
    float2* __restrict__ statsV, float2* __restrict__ statsA)
{
  const int blk  = blockIdx.x;
  const int s    = blk >> 8;
  const int b    = (blk >> 6) & 3;
  const int tile = blk & 63;
  const int wave = threadIdx.x >> 6, lane = threadIdx.x & 63;
  const float* x  = s ? xa : xv;
  const int* kpm  = s ? akpm : vkpm;
  float2* stp     = s ? statsA : statsV;
  const int row0  = b * TT + tile * 32 + wave * 8;

  __shared__ float lds[4][DD];

  // load 8 rows, build 16 reduction inputs (s1,s2 per row)
  float v[8][8];
  float a[16];
#pragma unroll
  for (int r = 0; r < 8; ++r) {
    ldf(x + (size_t)(row0 + r) * DD, lane, v[r]);
    float s1 = 0.f, s2 = 0.f;
#pragma unroll
    for (int k = 0; k < 8; ++k) { s1 += v[r][k]; s2 += v[r][k]*v[r][k]; }
    a[2*r]   = s1;
    a[2*r+1] = s2;
  }
  const float red = bfly16(a, lane);   // lane L: full sum of idx (L&15)

  // stats store: lane r (r<8) needs (s1_r, s2_r) = idx (2r, 2r+1)
  {
    const float sA = __shfl(red, (lane & 7) * 2);
    const float sB = __shfl(red, (lane & 7) * 2 + 1);
    const float meanW = sA * (1.f / (float)DD);
    const float rstdW = rsqrtf(sB * (1.f / (float)DD) - meanW*meanW + EPS);
    if (lane < 8) stp[row0 + lane] = make_float2(meanW, rstdW);
  }

  // masked accumulate of normalized rows (broadcasts are static-unrolled)
  float acc[8] = {0.f,0.f,0.f,0.f,0.f,0.f,0.f,0.f};
#pragma unroll
  for (int r = 0; r < 8; ++r) {
    const float s1r = __shfl(red, 2*r);
    const float s2r = __shfl(red, 2*r+1);
    const float mean = s1r * (1.f / (float)DD);
    const float rstd = rsqrtf(s2r * (1.f / (float)DD) - mean*mean + EPS);
    if (kpm[row0 + r] == 0) {          // wave-uniform
#pragma unroll
      for (int k = 0; k < 8; ++k) acc[k] += (v[r][k] - mean) * rstd;
    }
  }

#pragma unroll
  for (int k = 0; k < 4; ++k) {
    lds[wave][lane*4+k]       = acc[k];
    lds[wave][256+lane*4+k]   = acc[4+k];
  }
  __syncthreads();
  const int tid = threadIdx.x;
  float s0 = lds[0][tid] + lds[1][tid] + lds[2][tid] + lds[3][tid];
  float s1 = lds[0][tid+256] + lds[1][tid+256] + lds[2][tid+256] + lds[3][tid+256];
  float* p = partial + ((size_t)(s*4 + b) * 64 + tile) * DD;
  p[tid]       = s0;
  p[tid + 256] = s1;
}

// ---------------------------------------------------------------------------
// K2: per (p,b,h): inline S-reduce (L2), inline mask stats, ks via one
// 16-value butterfly per wave, m -> emitted pre-transformed:
//   mp = g*m; sm = sum(mp); c = sum(be*m).  layer-0 h==0 blocks write fs.
// Grid: 4*4*8 = 128 blocks, 256 threads.
// ---------------------------------------------------------------------------
__global__ __launch_bounds__(256) void mphase2_kernel(
    const float* __restrict__ partial,
    const int* __restrict__ vkpm, const int* __restrict__ akpm,
    const float* __restrict__ Wq_v, const float* __restrict__ Wk_av,
    const float* __restrict__ Wq_a, const float* __restrict__ Wk_va,
    const float* __restrict__ vid_g, const float* __restrict__ vid_b,
    const float* __restrict__ aud_g, const float* __restrict__ aud_b,
    float* __restrict__ mp,         // (4,4,8,512)
    float* __restrict__ cv,         // (4,4,8)
    float* __restrict__ smv,        // (4,4,8)
    float* __restrict__ fs)         // (8,4): {fac, flag, cnt}
{
  const int blk = blockIdx.x;
  const int p = blk >> 5, b = (blk >> 3) & 3, h = blk & 7;
  const int layer = p >> 1;
  const int isA = ((p & 1) == 0);   // A phases: vid queries, aud keys
  const int tid = threadIdx.x, wave = tid >> 6, lane = tid & 63;

  __shared__ float4 red4[256];
  __shared__ float nsum_s[DD];
  __shared__ float ksl[64];
  __shared__ float csh[4];
  __shared__ float cs2[4], ss2[4];

  const int ksb = (isA ? 1 : 0) * 4 + b;        // key side slot

  // inline S reduce over 64 tiles (t-split in halves, float4 per thread)
  {
    const int half = tid >> 7;                  // t in [0,32) or [32,64)
    const int i    = tid & 127;
    const float* pp = partial + ((size_t)ksb * 64 + half * 32) * DD + i * 4;
    float4 acc = make_float4(0.f, 0.f, 0.f, 0.f);
#pragma unroll 8
    for (int t = 0; t < 32; ++t) {
      float4 u = *reinterpret_cast<const float4*>(pp + (size_t)t * DD);
      acc.x += u.x; acc.y += u.y; acc.z += u.z; acc.w += u.w;
    }
    red4[tid] = acc;
  }

  // inline mask count
  const int* mk = isA ? akpm : vkpm;
  {
    int cnt = 0;
#pragma unroll
    for (int q = 0; q < 8; ++q) cnt += (mk[b * TT + q * 256 + tid] == 0) ? 1 : 0;
    float fc = wred((float)cnt);
    if (lane == 0) csh[wave] = fc;
  }
  __syncthreads();
  if (tid < 128) {
    float4 a0 = red4[tid], a1 = red4[tid + 128];
    *reinterpret_cast<float4*>(&nsum_s[tid * 4]) =
        make_float4(a0.x + a1.x, a0.y + a1.y, a0.z + a1.z, a0.w + a1.w);
  }
  __syncthreads();

  const float vc   = csh[0] + csh[1] + csh[2] + csh[3];
  const float fac  = SCALE / fmaxf(vc, 1.f);
  const float cntf = vc;
  if (layer == 0 && h == 0 && tid == 0) {   // p=0 -> ksb=4+b, p=1 -> ksb=b
    fs[ksb * 4 + 0] = fac;
    fs[ksb * 4 + 1] = (vc > 0.f) ? 1.f : 0.f;
    fs[ksb * 4 + 2] = vc;
  }

  const float* g  = (isA ? vid_g : aud_g) + (size_t)layer * DD;
  const float* be = (isA ? vid_b : aud_b) + (size_t)layer * DD;
  const float* Wk = (isA ? Wk_av : Wk_va) + (size_t)layer * WW;
  const float* Wq = (isA ? Wq_v  : Wq_a ) + (size_t)layer * WW;

  float gv[8], bv[8], sv[8], nl[8];
  ldf(g, lane, gv); ldf(be, lane, bv);
  {
    float4 aa = *reinterpret_cast<const float4*>(&nsum_s[lane * 4]);
    float4 cc = *reinterpret_cast<const float4*>(&nsum_s[256 + lane * 4]);
    sv[0]=aa.x; sv[1]=aa.y; sv[2]=aa.z; sv[3]=aa.w;
    sv[4]=cc.x; sv[5]=cc.y; sv[6]=cc.z; sv[7]=cc.w;
  }
#pragma unroll
  for (int k = 0; k < 8; ++k) nl[k] = sv[k]*gv[k] + cntf*bv[k];

  // ks: 16 dot-partials per wave -> ONE butterfly (was 16 serial wreds)
  {
    float a[16];
#pragma unroll
    for (int jj = 0; jj < 16; ++jj) {
      const int j = wave * 16 + jj;
      float w[8]; ldf(Wk + (size_t)(h*64 + j) * DD, lane, w);
      a[jj] = w[0]*nl[0]+w[1]*nl[1]+w[2]*nl[2]+w[3]*nl[3]
            + w[4]*nl[4]+w[5]*nl[5]+w[6]*nl[6]+w[7]*nl[7];
    }
    const float red = bfly16(a, lane);     // lane L: dot idx (L&15)
    if (lane < 16) ksl[wave * 16 + lane] = red * fac;
  }
  __syncthreads();

  float a0 = 0.f, a1 = 0.f;
  const float* base = Wq + (size_t)(h*64) * DD;
#pragma unroll 16
  for (int j = 0; j < 64; ++j) {
    const float kk = ksl[j];
    a0 += base[(size_t)j*DD + tid]       * kk;
    a1 += base[(size_t)j*DD + tid + 256] * kk;
  }

  // transform: mp = g*m; scalars c = sum be*m, sm = sum mp
  const float gq0 = g[tid], gq1 = g[tid + 256];
  const float bq0 = be[tid], bq1 = be[tid + 256];
  const float mp0 = a0 * gq0, mp1 = a1 * gq1;
  float* mo = mp + (((size_t)p*4 + b)*8 + h) * DD;
  mo[tid]       = mp0;
  mo[tid + 256] = mp1;

  float cp = a0*bq0 + a1*bq1;
  float sp = mp0 + mp1;
  cp = wred(cp); sp = wred(sp);
  if (lane == 0) { cs2[wave] = cp; ss2[wave] = sp; }
  __syncthreads();
  if (tid == 0) {
    const int idx = ((p*4 + b)*8 + h);
    cv[idx]  = cs2[0]+cs2[1]+cs2[2]+cs2[3];
    smv[idx] = ss2[0]+ss2[1]+ss2[2]+ss2[3];
  }
}

// ---------------------------------------------------------------------------
// K3: final gates + output. 2 rows per wave, 8 per block (R9 geometry, best
// measured); per-row stats LOADED (uniform) instead of recomputed.
// 32 dot partials -> 32-value halving butterfly; MLP lane-parallel, lanes 0..3.
// Grid: 2*4*256 = 2048 blocks, 256 threads.
// ---------------------------------------------------------------------------
__global__ __launch_bounds__(256) void final_kernel(
    const float* __restrict__ xv_in, const float* __restrict__ xa_in,
    const float2* __restrict__ statsV, const float2* __restrict__ statsA,
    const float* __restrict__ mp, const float* __restrict__ cv,
    const float* __restrict__ smv, const float* __restrict__ fs,
    const float* __restrict__ vg_W1, const float* __restrict__ vg_b1,
    const float* __restrict__ vg_W2, const float* __restrict__ vg_b2,
    const float* __restrict__ ag_W1, const float* __restrict__ ag_b1,
    const float* __restrict__ ag_W2, const float* __restrict__ ag_b2,
    float* __restrict__ out_v, float* __restrict__ out_a)
{
  const int blk = blockIdx.x;
  const int s = blk >> 10, b = (blk >> 8) & 3, tile = blk & 255;
  const int tid = threadIdx.x, lane = tid & 63;
  const int wave = tid >> 6;
  const float* x = s ? xa_in : xv_in;
  const float2* st = s ? statsA : statsV;
  float* out     = s ? out_a : out_v;
  const int row0 = b * TT + tile * 8 + wave * 2;

  // stage both layers' MLP params once
  __shared__ float mlp[2][161];
  {
    const float* W1p = s ? ag_W1 : vg_W1;   // (2,16,8)
    const float* b1p = s ? ag_b1 : vg_b1;   // (2,16)
    const float* W2p = s ? ag_W2 : vg_W2;   // (2,16)
    const float* b2p = s ? ag_b2 : vg_b2;   // (2)
    if (tid < 128)       { mlp[0][tid] = W1p[tid];       mlp[1][tid] = W1p[128 + tid]; }
    else if (tid < 144)  { mlp[0][tid] = b1p[tid - 128]; mlp[1][tid] = b1p[tid - 112]; }
    else if (tid < 160)  { mlp[0][tid] = W2p[tid - 144]; mlp[1][tid] = W2p[tid - 128]; }
    else if (tid == 160) { mlp[0][160] = b2p[0];         mlp[1][160] = b2p[1]; }
  }
  __syncthreads();

  const float flag = fs[(((s ? 0 : 1) * 4) + b) * 4 + 1];   // key-mask side

  // per-row stats: uniform loads (written by sums_kernel)
  const float2 st0 = st[row0];
  const float2 st1 = st[row0 + 1];

  float v[2][8];
  ldf(x + (size_t)(row0 + 0) * DD, lane, v[0]);
  ldf(x + (size_t)(row0 + 1) * DD, lane, v[1]);

  // 32 dot partials: a[r*16 + l*8 + h] = v[r] . mp[l,h] (this lane's 8 elems)
  float a[32];
  const float* mpb0 = mp + ((size_t)(s*4 + b) * 8) * DD;        // l=0 -> p=s
  const float* mpb1 = mp + ((size_t)((2+s)*4 + b) * 8) * DD;    // l=1 -> p=2+s
#pragma unroll
  for (int l = 0; l < 2; ++l) {
    const float* mb_ = l ? mpb1 : mpb0;
#pragma unroll
    for (int h = 0; h < HH; ++h) {
      float w[8]; ldf(mb_ + (size_t)h * DD, lane, w);
      const int j = l*8 + h;
#pragma unroll
      for (int r = 0; r < 2; ++r) {
        a[r*16 + j] = v[r][0]*w[0] + v[r][1]*w[1] + v[r][2]*w[2] + v[r][3]*w[3]
                    + v[r][4]*w[4] + v[r][5]*w[5] + v[r][6]*w[6] + v[r][7]*w[7];
      }
    }
  }

  // halving butterfly over 32 values; lane L ends with full dot idx (L&31)
#pragma unroll
  for (int k = 0; k < 5; ++k) {
    const int bit = (lane >> k) & 1;
#pragma unroll
    for (int m = 0; m < (32 >> (k + 1)); ++m) {
      const float keep = bit ? a[2*m+1] : a[2*m];
      const float send = bit ? a[2*m]   : a[2*m+1];
      a[m] = keep + __shfl_xor(send, 1 << k);
    }
  }
  const float dotv = a[0] + __shfl_xor(a[0], 32);

  // gather: job lane jl in 0..3 -> (r = jl&1, l = jl>>1); dots at lanes
  // r*16 + l*8 + h. Executed by ALL lanes (shfl needs full wave).
  const int gr = lane & 1, gl = (lane >> 1) & 1;
  float q[8];
#pragma unroll
  for (int h = 0; h < HH; ++h) q[h] = __shfl(dotv, gr*16 + gl*8 + h);

  float gpart = 1.f;
  if (lane < 4) {
    const int l = lane >> 1;
    const int r = lane & 1;
    const float myMean = r ? st1.x : st0.x;
    const float myRstd = r ? st1.y : st0.y;
    const int p = l*2 + s;
    const float* cb  = cv  + ((size_t)p*4 + b) * 8;
    const float* sbv = smv + ((size_t)p*4 + b) * 8;
    float rel[8];
#pragma unroll
    for (int h = 0; h < HH; ++h)
      rel[h] = myRstd * (q[h] - myMean * sbv[h]) + cb[h];
    float z = mlp[l][160];
#pragma unroll
    for (int e = 0; e < 16; ++e) {
      float h1 = mlp[l][128 + e];
#pragma unroll
      for (int h = 0; h < HH; ++h) h1 += rel[h] * mlp[l][e*8 + h];
      z += fmaxf(h1, 0.f) * mlp[l][144 + e];
    }
    gpart = 1.f + flag * (1.f / (1.f + expf(-z)));
  }

#pragma unroll
  for (int r = 0; r < 2; ++r) {
    const float sc = __shfl(gpart, r) * __shfl(gpart, 2 + r);
    float* orow = out + (size_t)(row0 + r) * DD;
    *reinterpret_cast<float4*>(orow + lane*4) =
        make_float4(v[r][0]*sc, v[r][1]*sc, v[r][2]*sc, v[r][3]*sc);
    *reinterpret_cast<float4*>(orow + 256 + lane*4) =
        make_float4(v[r][4]*sc, v[r][5]*sc, v[r][6]*sc, v[r][7]*sc);
  }
}

// ---------------------------------------------------------------------------
extern "C" void kernel_launch(void* const* d_in, const int* in_sizes, int n_in,
                              void* d_out, int out_size, void* d_ws, size_t ws_size,
                              hipStream_t stream) {
  const float* x_vid = (const float*)d_in[0];
  const float* x_aud = (const float*)d_in[1];
  const int* vid_kpm = (const int*)d_in[2];
  const int* aud_kpm = (const int*)d_in[3];
  const float* Wq_vid         = (const float*)d_in[4];
  const float* Wk_aud_for_vid = (const float*)d_in[5];
  const float* Wq_aud         = (const float*)d_in[6];
  const float* Wk_vid_for_aud = (const float*)d_in[7];
  const float* vg_W1 = (const float*)d_in[8];
  const float* vg_b1 = (const float*)d_in[9];
  const float* vg_W2 = (const float*)d_in[10];
  const float* vg_b2 = (const float*)d_in[11];
  const float* ag_W1 = (const float*)d_in[12];
  const float* ag_b1 = (const float*)d_in[13];
  const float* ag_W2 = (const float*)d_in[14];
  const float* ag_b2 = (const float*)d_in[15];
  const float* vid_ln_g = (const float*)d_in[16];
  const float* vid_ln_b = (const float*)d_in[17];
  const float* aud_ln_g = (const float*)d_in[18];
  const float* aud_ln_b = (const float*)d_in[19];

  const size_t BTD = (size_t)BB * TT * DD;
  float* out_v = (float*)d_out;
  float* out_a = out_v + BTD;

  float* partial = (float*)d_ws;                       // 2*4*64*512 = 1 MB
  float* fs      = partial + (size_t)8 * 64 * DD;      // 8*4
  float* mpw     = fs + 32;                            // 4*4*8*512 = 256 KB
  float* cvw     = mpw + (size_t)4 * 4 * 8 * DD;       // 128
  float* smw     = cvw + 128;                          // 128
  float2* statsV = (float2*)(smw + 128);               // 8192 float2 (64 KB)
  float2* statsA = statsV + (size_t)BB * TT;           // 8192 float2 (64 KB)

  sums_kernel<<<512, 256, 0, stream>>>(
      x_vid, x_aud, vid_kpm, aud_kpm, partial, statsV, statsA);
  mphase2_kernel<<<128, 256, 0, stream>>>(
      partial, vid_kpm, aud_kpm,
      Wq_vid, Wk_aud_for_vid, Wq_aud, Wk_vid_for_aud,
      vid_ln_g, vid_ln_b, aud_ln_g, aud_ln_b, mpw, cvw, smw, fs);
  final_kernel<<<2048, 256, 0, stream>>>(
      x_vid, x_aud, statsV, statsA, mpw, cvw, smw, fs,
      vg_W1, vg_b1, vg_W2, vg_b2, ag_W1, ag_b1, ag_W2, ag_b2,
      out_v, out_a);
}